// Round 1
// baseline (181.861 us; speedup 1.0000x reference)
//
#include <hip/hip_runtime.h>
#include <hip/hip_bf16.h>
#include <stdint.h>

// Problem: B=4, N=8192, C=512, HEADS=8, d=64.
// qkv = x @ w_qkv.T + b_qkv          -> (32768, 1536) = [q|k|v] each (8 heads x 64)
// per-token: dots[h][g] = q[h]·k[g]/8, clip +-50, softmax over g, out[h] = sum_g attn*v[g]
// scramble:  prefc[b, h*1024 + n/8, (n%8)*64 + d] = out[b, n, h, d]
// final:     out = prefc @ w_fc.T + b_fc   (f32 output)

typedef __bf16 bf16x8 __attribute__((ext_vector_type(8)));
typedef float f32x4 __attribute__((ext_vector_type(4)));

__device__ __forceinline__ unsigned short f2bf(float f) {
  unsigned u = __float_as_uint(f);
  u += 0x7fffu + ((u >> 16) & 1u);   // round-to-nearest-even
  return (unsigned short)(u >> 16);
}
__device__ __forceinline__ unsigned pk2(float a, float b) {
  return (unsigned)f2bf(a) | ((unsigned)f2bf(b) << 16);
}
__device__ __forceinline__ void unpk2(unsigned u, float& a, float& b) {
  a = __uint_as_float(u << 16);
  b = __uint_as_float(u & 0xffff0000u);
}

__device__ __forceinline__ void gload_lds16(const void* g, void* l) {
  __builtin_amdgcn_global_load_lds((const __attribute__((address_space(1))) void*)g,
                                   (__attribute__((address_space(3))) void*)l,
                                   16, 0, 0);
}

// ---------------- f32 -> bf16 convert (vectorized, 8 elem/thread) ----------------
__global__ __launch_bounds__(256) void cvt_f32_to_bf16(const float* __restrict__ in,
                                                       __hip_bfloat16* __restrict__ out,
                                                       int n8) {
  int i = blockIdx.x * 256 + threadIdx.x;
  if (i >= n8) return;
  const float4* p = (const float4*)in;
  float4 a = p[i * 2];
  float4 b = p[i * 2 + 1];
  uint4 o;
  o.x = pk2(a.x, a.y);
  o.y = pk2(a.z, a.w);
  o.z = pk2(b.x, b.y);
  o.w = pk2(b.z, b.w);
  ((uint4*)out)[i] = o;
}

// ---------------- bf16 GEMM, C = A @ B^T + bias ----------------
// A: M x K (row-major bf16), B: N x K (row-major bf16), bias: N (f32)
// 128x128 tile, BK=64, 4 waves (2x2 of 64x64), 16x16x32 MFMA, global_load_lds staging.
template <bool OUT_BF16>
__global__ __launch_bounds__(256) void gemm_bt(const __hip_bfloat16* __restrict__ A,
                                               const __hip_bfloat16* __restrict__ Bm,
                                               const float* __restrict__ bias,
                                               void* __restrict__ C,
                                               int M, int N, int K, int NT) {
  __shared__ __hip_bfloat16 sA[128 * 64];
  __shared__ __hip_bfloat16 sB[128 * 64];

  const int tid = threadIdx.x;
  const int wv = tid >> 6;
  const int ln = tid & 63;
  const int bid = blockIdx.x;
  const int mt = bid / NT, nt = bid % NT;
  const int bm0 = mt * 128, bn0 = nt * 128;
  const int lrow = ln & 15;   // fragment row (A) / col (B,D)
  const int kg = ln >> 4;     // k-group 0..3
  const int wm = wv >> 1, wn = wv & 1;

  f32x4 acc[4][4] = {};

  // staging geometry: tile is 128 rows x 64 cols bf16 = 128 B/row, 16 KiB.
  // issue i: wave wv covers LDS bytes [(i*4+wv)*1024, +1024), lane adds ln*16.
  int srow[4], scol[4], sbase[4];
  for (int i = 0; i < 4; ++i) {
    int ofs = (i * 4 + wv) * 1024 + ln * 16;
    srow[i] = ofs >> 7;
    scol[i] = (ofs & 127) >> 1;
    sbase[i] = (i * 4 + wv) * 512;  // element offset, wave-uniform
  }

  for (int k0 = 0; k0 < K; k0 += 64) {
    for (int i = 0; i < 4; ++i) {
      gload_lds16(A + (size_t)(bm0 + srow[i]) * K + k0 + scol[i], sA + sbase[i]);
      gload_lds16(Bm + (size_t)(bn0 + srow[i]) * K + k0 + scol[i], sB + sbase[i]);
    }
    __syncthreads();
#pragma unroll
    for (int ks = 0; ks < 2; ++ks) {
      bf16x8 af[4], bfr[4];
#pragma unroll
      for (int i = 0; i < 4; ++i) {
        af[i] = *(const bf16x8*)(sA + (wm * 64 + i * 16 + lrow) * 64 + ks * 32 + kg * 8);
        bfr[i] = *(const bf16x8*)(sB + (wn * 64 + i * 16 + lrow) * 64 + ks * 32 + kg * 8);
      }
#pragma unroll
      for (int i = 0; i < 4; ++i)
#pragma unroll
        for (int j = 0; j < 4; ++j)
          acc[i][j] = __builtin_amdgcn_mfma_f32_16x16x32_bf16(af[i], bfr[j], acc[i][j], 0, 0, 0);
    }
    __syncthreads();
  }

  // epilogue: D mapping col=lane&15, row=(lane>>4)*4+r
#pragma unroll
  for (int j = 0; j < 4; ++j) {
    int col = bn0 + wn * 64 + j * 16 + lrow;
    float bv = bias[col];
#pragma unroll
    for (int i = 0; i < 4; ++i) {
      int row0 = bm0 + wm * 64 + i * 16 + kg * 4;
#pragma unroll
      for (int r = 0; r < 4; ++r) {
        float v = acc[i][j][r] + bv;
        size_t idx = (size_t)(row0 + r) * N + col;
        if (OUT_BF16) {
          unsigned short us = f2bf(v);
          ((unsigned short*)C)[idx] = us;
        } else {
          ((float*)C)[idx] = v;
        }
      }
    }
  }
}

// ---------------- per-token attention, 1 token per wave, register-only ----------------
// lane l = h*8 + m holds elements d in [m*8, m*8+8) of head h for q,k,v.
__global__ __launch_bounds__(256) void attn_tok(const __hip_bfloat16* __restrict__ qkv,
                                                __hip_bfloat16* __restrict__ outp,
                                                int ntok, int npb) {
  const int wv = threadIdx.x >> 6;
  const int ln = threadIdx.x & 63;
  const int t = blockIdx.x * 4 + wv;
  if (t >= ntok) return;
  const int m = ln & 7;

  const __hip_bfloat16* row = qkv + (size_t)t * 1536;
  uint4 qr = *(const uint4*)(row + ln * 8);
  uint4 kr = *(const uint4*)(row + 512 + ln * 8);
  uint4 vr = *(const uint4*)(row + 1024 + ln * 8);

  float qf[8];
  unpk2(qr.x, qf[0], qf[1]);
  unpk2(qr.y, qf[2], qf[3]);
  unpk2(qr.z, qf[4], qf[5]);
  unpk2(qr.w, qf[6], qf[7]);
  unsigned kw[4] = {kr.x, kr.y, kr.z, kr.w};
  unsigned vw[4] = {vr.x, vr.y, vr.z, vr.w};

  // dots[g] for this lane's head h (all 8 lanes of the h-group end up with the full row)
  float dt[8];
#pragma unroll
  for (int g = 0; g < 8; ++g) {
    int src = g * 8 + m;
    float s = 0.f;
#pragma unroll
    for (int j4 = 0; j4 < 4; ++j4) {
      unsigned kk = __shfl(kw[j4], src, 64);
      float a, b;
      unpk2(kk, a, b);
      s += qf[j4 * 2] * a + qf[j4 * 2 + 1] * b;
    }
    s += __shfl_xor(s, 1, 64);
    s += __shfl_xor(s, 2, 64);
    s += __shfl_xor(s, 4, 64);
    dt[g] = s;
  }

  // softmax over g (clip to +-50 as in reference)
  float mx = -1e30f;
#pragma unroll
  for (int g = 0; g < 8; ++g) {
    dt[g] = fminf(fmaxf(dt[g] * 0.125f, -50.f), 50.f);
    mx = fmaxf(mx, dt[g]);
  }
  float p[8], ssum = 0.f;
#pragma unroll
  for (int g = 0; g < 8; ++g) {
    p[g] = __expf(dt[g] - mx);
    ssum += p[g];
  }
  float inv = 1.f / ssum;

  // out[h][m*8+j] = sum_g attn[g] * v[g][m*8+j]
  float o[8] = {0, 0, 0, 0, 0, 0, 0, 0};
#pragma unroll
  for (int g = 0; g < 8; ++g) {
    int src = g * 8 + m;
    float ag = p[g] * inv;
#pragma unroll
    for (int j4 = 0; j4 < 4; ++j4) {
      unsigned vv = __shfl(vw[j4], src, 64);
      float a, b;
      unpk2(vv, a, b);
      o[j4 * 2] += ag * a;
      o[j4 * 2 + 1] += ag * b;
    }
  }

  // scrambled store: row_b = h*(npb/8) + n/8, col = (n%8)*64 + m*8
  const int h = ln >> 3;
  const int b = t / npb, n = t % npb;
  size_t dst = (size_t)b * npb * 512 + (size_t)(h * (npb >> 3) + (n >> 3)) * 512 +
               (size_t)((n & 7) * 64 + m * 8);
  uint4 ov;
  ov.x = pk2(o[0], o[1]);
  ov.y = pk2(o[2], o[3]);
  ov.z = pk2(o[4], o[5]);
  ov.w = pk2(o[6], o[7]);
  *(uint4*)(outp + dst) = ov;
}

// ---------------- launch ----------------
extern "C" void kernel_launch(void* const* d_in, const int* in_sizes, int n_in,
                              void* d_out, int out_size, void* d_ws, size_t ws_size,
                              hipStream_t stream) {
  const float* x = (const float*)d_in[0];      // 32768 x 512
  const float* w_qkv = (const float*)d_in[1];  // 1536 x 512
  const float* b_qkv = (const float*)d_in[2];  // 1536
  const float* w_fc = (const float*)d_in[3];   // 512 x 512
  const float* b_fc = (const float*)d_in[4];   // 512
  float* out = (float*)d_out;

  const int M = 32768;  // B*N tokens
  const int Cc = 512, N3 = 1536;

  __hip_bfloat16* xb = (__hip_bfloat16*)d_ws;               // 16.8M elems
  __hip_bfloat16* wqkvb = xb + (size_t)M * Cc;              // 786432
  __hip_bfloat16* wfcb = wqkvb + (size_t)N3 * Cc;           // 262144
  __hip_bfloat16* qkvb = wfcb + (size_t)Cc * Cc;            // 50.3M elems
  __hip_bfloat16* attb = qkvb + (size_t)M * N3;             // 16.8M elems

  cvt_f32_to_bf16<<<(M * Cc / 8) / 256, 256, 0, stream>>>(x, xb, M * Cc / 8);
  cvt_f32_to_bf16<<<(N3 * Cc / 8) / 256, 256, 0, stream>>>(w_qkv, wqkvb, N3 * Cc / 8);
  cvt_f32_to_bf16<<<(Cc * Cc / 8) / 256, 256, 0, stream>>>(w_fc, wfcb, Cc * Cc / 8);

  gemm_bt<true><<<(M / 128) * (N3 / 128), 256, 0, stream>>>(xb, wqkvb, b_qkv, qkvb, M, N3, Cc,
                                                            N3 / 128);
  attn_tok<<<M / 4, 256, 0, stream>>>(qkvb, attb, M, 8192);
  gemm_bt<false><<<(M / 128) * (Cc / 128), 256, 0, stream>>>(attb, wfcb, b_fc, out, M, Cc, Cc,
                                                             Cc / 128);
}

// Round 2
// 168.030 us; speedup vs baseline: 1.0823x; 1.0823x over previous
//
#include <hip/hip_runtime.h>
#include <hip/hip_bf16.h>
#include <stdint.h>

// MHSA: B=4, N=8192, C=512, HEADS=8, d=64.
// qkv = x @ w_qkv.T + b_qkv ; per-token 8x8 head-mix softmax ; scramble ; @ w_fc.T + b_fc
//
// GEMMs use the 256x256 8-phase template (T1..T5): BK=64 as two 32-wide K-halves,
// 8 waves (2Mx4N), 128 KiB LDS double-buffer, global_load_lds(16B) staging with
// pre-swizzled SOURCE addresses (linear LDS dest), counted vmcnt(4) at phases 4/8.

typedef __bf16 bf16x8 __attribute__((ext_vector_type(8)));
typedef float f32x4 __attribute__((ext_vector_type(4)));

__device__ __forceinline__ unsigned short f2bf(float f) {
  unsigned u = __float_as_uint(f);
  u += 0x7fffu + ((u >> 16) & 1u);  // RNE
  return (unsigned short)(u >> 16);
}
__device__ __forceinline__ unsigned pk2(float a, float b) {
  return (unsigned)f2bf(a) | ((unsigned)f2bf(b) << 16);
}
__device__ __forceinline__ void unpk2(unsigned u, float& a, float& b) {
  a = __uint_as_float(u << 16);
  b = __uint_as_float(u & 0xffff0000u);
}
__device__ __forceinline__ void gload_lds16(const void* g, void* l) {
  __builtin_amdgcn_global_load_lds((const __attribute__((address_space(1))) void*)g,
                                   (__attribute__((address_space(3))) void*)l,
                                   16, 0, 0);
}

// ---------------- f32 -> bf16 convert ----------------
__global__ __launch_bounds__(256) void cvt_f32_to_bf16(const float* __restrict__ in,
                                                       __hip_bfloat16* __restrict__ out,
                                                       int n8) {
  int i = blockIdx.x * 256 + threadIdx.x;
  if (i >= n8) return;
  const float4* p = (const float4*)in;
  float4 a = p[i * 2];
  float4 b = p[i * 2 + 1];
  uint4 o;
  o.x = pk2(a.x, a.y);
  o.y = pk2(a.z, a.w);
  o.z = pk2(b.x, b.y);
  o.w = pk2(b.z, b.w);
  ((uint4*)out)[i] = o;
}

// ---------------- 256x256 8-phase bf16 GEMM, C = A @ B^T + bias ----------------
// A: M x K bf16, B: N x K bf16 (row-major), bias: N f32.
// LDS region (16 KiB) holds one K-half (256 rows x 32 k-elems).
// Physical swizzle: P(lr,t) = (lr>>1)*128 + ((((lr&1)<<2)|t) ^ ((lr>>1)&7))*16.

#define STAGEH(SBUF, ISA, SKH, KT)                                                        \
  do {                                                                                    \
    const __hip_bfloat16* _sp = (ISA) ? Ag : Bg;                                          \
    int _r0 = (ISA) ? bm0 : bn0;                                                          \
    _Pragma("unroll") for (int _j = 0; _j < 2; ++_j) {                                    \
      gload_lds16(_sp + (size_t)(_r0 + srow[_j]) * K + (KT) * 64 + (SKH) * 32 + skoff[_j],\
                  lds + (SBUF) * 65536 + ((ISA) ? 0 : 32768) + (SKH) * 16384 +            \
                      destoff[_j]);                                                       \
    }                                                                                     \
  } while (0)

#define PHASE(BUF, KS, FH, SBUF, SISA, SKH, KT, DOW)                                      \
  do {                                                                                    \
    const char* _ab = lds + (BUF) * 65536 + (KS) * 16384 + wm * 8192 + (FH) * 4096 + pbase;\
    bf16x8 _af0 = *(const bf16x8*)(_ab);                                                  \
    bf16x8 _af1 = *(const bf16x8*)(_ab + 1024);                                           \
    bf16x8 _af2 = *(const bf16x8*)(_ab + 2048);                                           \
    bf16x8 _af3 = *(const bf16x8*)(_ab + 3072);                                           \
    if (FH == 0) {                                                                        \
      const char* _bb = lds + (BUF) * 65536 + 32768 + (KS) * 16384 + wn * 4096 + pbase;   \
      bfr[0] = *(const bf16x8*)(_bb);                                                     \
      bfr[1] = *(const bf16x8*)(_bb + 1024);                                              \
      bfr[2] = *(const bf16x8*)(_bb + 2048);                                              \
      bfr[3] = *(const bf16x8*)(_bb + 3072);                                              \
    }                                                                                     \
    STAGEH(SBUF, SISA, SKH, KT);                                                          \
    __builtin_amdgcn_s_barrier();                                                         \
    asm volatile("s_waitcnt lgkmcnt(0)" ::: "memory");                                    \
    __builtin_amdgcn_sched_barrier(0);                                                    \
    __builtin_amdgcn_s_setprio(1);                                                        \
    _Pragma("unroll") for (int _c = 0; _c < 4; ++_c) {                                    \
      acc[(FH) * 4 + 0][_c] =                                                             \
          __builtin_amdgcn_mfma_f32_16x16x32_bf16(_af0, bfr[_c], acc[(FH) * 4 + 0][_c], 0, 0, 0); \
      acc[(FH) * 4 + 1][_c] =                                                             \
          __builtin_amdgcn_mfma_f32_16x16x32_bf16(_af1, bfr[_c], acc[(FH) * 4 + 1][_c], 0, 0, 0); \
      acc[(FH) * 4 + 2][_c] =                                                             \
          __builtin_amdgcn_mfma_f32_16x16x32_bf16(_af2, bfr[_c], acc[(FH) * 4 + 2][_c], 0, 0, 0); \
      acc[(FH) * 4 + 3][_c] =                                                             \
          __builtin_amdgcn_mfma_f32_16x16x32_bf16(_af3, bfr[_c], acc[(FH) * 4 + 3][_c], 0, 0, 0); \
    }                                                                                     \
    __builtin_amdgcn_s_setprio(0);                                                        \
    if (DOW) {                                                                            \
      asm volatile("s_waitcnt vmcnt(4)" ::: "memory");                                    \
    }                                                                                     \
    __builtin_amdgcn_s_barrier();                                                         \
    __builtin_amdgcn_sched_barrier(0);                                                    \
  } while (0)

template <bool OUT_BF16>
__global__ __launch_bounds__(512, 2) void gemm8(const __hip_bfloat16* __restrict__ Ag,
                                                const __hip_bfloat16* __restrict__ Bg,
                                                const float* __restrict__ bias,
                                                void* __restrict__ C,
                                                int M, int N, int K, int NT) {
  __shared__ char lds[131072];  // [buf:2][A/B][khalf:2][16KiB]

  const int tid = threadIdx.x;
  const int wv = tid >> 6;
  const int ln = tid & 63;
  const int lrow = ln & 15;
  const int kg = ln >> 4;
  const int wm = wv >> 2;   // 0..1 -> 128-row panel
  const int wn = wv & 3;    // 0..3 -> 64-col panel

  // XCD-aware bijective swizzle (gridDim.x % 8 == 0 guaranteed by launch)
  int nwg = gridDim.x;
  int cpx = nwg >> 3;
  int bs = (blockIdx.x & 7) * cpx + (blockIdx.x >> 3);
  const int bm0 = (bs / NT) * 256;
  const int bn0 = (bs % NT) * 256;

  // fragment-read swizzled per-lane base (within a 16KiB K-half region)
  const int pbase = (lrow >> 1) * 128 + ((((lrow & 1) << 2) | kg) ^ ((lrow >> 1) & 7)) * 16;

  // staging geometry: issue j covers linear LDS bytes [j*8192 + wv*1024 + ln*16)
  int srow[2], skoff[2], destoff[2];
#pragma unroll
  for (int j = 0; j < 2; ++j) {
    int L = j * 8192 + wv * 1024 + ln * 16;
    int rp = L >> 7;
    int T = ((L >> 4) & 7) ^ (rp & 7);
    srow[j] = rp * 2 + (T >> 2);
    skoff[j] = (T & 3) * 8;
    destoff[j] = j * 8192 + wv * 1024;  // wave-uniform; HW adds ln*16
  }

  f32x4 acc[8][4] = {};
  bf16x8 bfr[4];

  const int NKT = K >> 6;   // 64-wide K-tiles (8 for K=512)
  const int NI = NKT >> 1;  // 2 K-tiles per iteration

  // prologue: tile0 (buf0) fully + tile1 (buf1) K-half0
  STAGEH(0, 1, 0, 0);
  STAGEH(0, 0, 0, 0);
  STAGEH(0, 1, 1, 0);
  STAGEH(0, 0, 1, 0);
  STAGEH(1, 1, 0, 1);
  STAGEH(1, 0, 0, 1);
  asm volatile("s_waitcnt vmcnt(4)" ::: "memory");
  __builtin_amdgcn_s_barrier();
  __builtin_amdgcn_sched_barrier(0);

  for (int i = 0; i < NI; ++i) {
    int kt1 = 2 * i + 1;
    int kt2 = 2 * i + 2 < NKT ? 2 * i + 2 : NKT - 1;
    int kt3 = 2 * i + 3 < NKT ? 2 * i + 3 : NKT - 1;
    PHASE(0, 0, 0, /*stage*/ 1, 1, 1, kt1, 0);
    PHASE(0, 0, 1, /*stage*/ 1, 0, 1, kt1, 0);
    PHASE(0, 1, 0, /*stage*/ 0, 1, 0, kt2, 0);
    PHASE(0, 1, 1, /*stage*/ 0, 0, 0, kt2, 1);
    PHASE(1, 0, 0, /*stage*/ 0, 1, 1, kt2, 0);
    PHASE(1, 0, 1, /*stage*/ 0, 0, 1, kt2, 0);
    PHASE(1, 1, 0, /*stage*/ 1, 1, 0, kt3, 0);
    PHASE(1, 1, 1, /*stage*/ 1, 0, 0, kt3, 1);
  }
  asm volatile("s_waitcnt vmcnt(0)" ::: "memory");

  // epilogue: D mapping col=lane&15, row=(lane>>4)*4+r
#pragma unroll
  for (int cj = 0; cj < 4; ++cj) {
    int col = bn0 + wn * 64 + cj * 16 + lrow;
    float bv = bias[col];
#pragma unroll
    for (int fi = 0; fi < 8; ++fi) {
      int row0 = bm0 + wm * 128 + fi * 16 + kg * 4;
#pragma unroll
      for (int r = 0; r < 4; ++r) {
        float v = acc[fi][cj][r] + bv;
        size_t idx = (size_t)(row0 + r) * N + col;
        if (OUT_BF16) {
          ((unsigned short*)C)[idx] = f2bf(v);
        } else {
          ((float*)C)[idx] = v;
        }
      }
    }
  }
}

// ---------------- per-token attention, 1 token per wave ----------------
__global__ __launch_bounds__(256) void attn_tok(const __hip_bfloat16* __restrict__ qkv,
                                                __hip_bfloat16* __restrict__ outp,
                                                int ntok, int npb) {
  const int wv = threadIdx.x >> 6;
  const int ln = threadIdx.x & 63;
  const int t = blockIdx.x * 4 + wv;
  if (t >= ntok) return;
  const int m = ln & 7;

  const __hip_bfloat16* row = qkv + (size_t)t * 1536;
  uint4 qr = *(const uint4*)(row + ln * 8);
  uint4 kr = *(const uint4*)(row + 512 + ln * 8);
  uint4 vr = *(const uint4*)(row + 1024 + ln * 8);

  float qf[8];
  unpk2(qr.x, qf[0], qf[1]);
  unpk2(qr.y, qf[2], qf[3]);
  unpk2(qr.z, qf[4], qf[5]);
  unpk2(qr.w, qf[6], qf[7]);
  unsigned kw[4] = {kr.x, kr.y, kr.z, kr.w};
  unsigned vw[4] = {vr.x, vr.y, vr.z, vr.w};

  float dt[8];
#pragma unroll
  for (int g = 0; g < 8; ++g) {
    int src = g * 8 + m;
    float s = 0.f;
#pragma unroll
    for (int j4 = 0; j4 < 4; ++j4) {
      unsigned kk = __shfl(kw[j4], src, 64);
      float a, b;
      unpk2(kk, a, b);
      s += qf[j4 * 2] * a + qf[j4 * 2 + 1] * b;
    }
    s += __shfl_xor(s, 1, 64);
    s += __shfl_xor(s, 2, 64);
    s += __shfl_xor(s, 4, 64);
    dt[g] = s;
  }

  float mx = -1e30f;
#pragma unroll
  for (int g = 0; g < 8; ++g) {
    dt[g] = fminf(fmaxf(dt[g] * 0.125f, -50.f), 50.f);
    mx = fmaxf(mx, dt[g]);
  }
  float p[8], ssum = 0.f;
#pragma unroll
  for (int g = 0; g < 8; ++g) {
    p[g] = __expf(dt[g] - mx);
    ssum += p[g];
  }
  float inv = 1.f / ssum;

  float o[8] = {0, 0, 0, 0, 0, 0, 0, 0};
#pragma unroll
  for (int g = 0; g < 8; ++g) {
    int src = g * 8 + m;
    float ag = p[g] * inv;
#pragma unroll
    for (int j4 = 0; j4 < 4; ++j4) {
      unsigned vv = __shfl(vw[j4], src, 64);
      float a, b;
      unpk2(vv, a, b);
      o[j4 * 2] += ag * a;
      o[j4 * 2 + 1] += ag * b;
    }
  }

  const int h = ln >> 3;
  const int b = t / npb, n = t % npb;
  size_t dst = (size_t)b * npb * 512 + (size_t)(h * (npb >> 3) + (n >> 3)) * 512 +
               (size_t)((n & 7) * 64 + m * 8);
  uint4 ov;
  ov.x = pk2(o[0], o[1]);
  ov.y = pk2(o[2], o[3]);
  ov.z = pk2(o[4], o[5]);
  ov.w = pk2(o[6], o[7]);
  *(uint4*)(outp + dst) = ov;
}

// ---------------- launch ----------------
extern "C" void kernel_launch(void* const* d_in, const int* in_sizes, int n_in,
                              void* d_out, int out_size, void* d_ws, size_t ws_size,
                              hipStream_t stream) {
  const float* x = (const float*)d_in[0];
  const float* w_qkv = (const float*)d_in[1];
  const float* b_qkv = (const float*)d_in[2];
  const float* w_fc = (const float*)d_in[3];
  const float* b_fc = (const float*)d_in[4];
  float* out = (float*)d_out;

  const int M = 32768;
  const int Cc = 512, N3 = 1536;

  __hip_bfloat16* xb = (__hip_bfloat16*)d_ws;
  __hip_bfloat16* wqkvb = xb + (size_t)M * Cc;
  __hip_bfloat16* wfcb = wqkvb + (size_t)N3 * Cc;
  __hip_bfloat16* qkvb = wfcb + (size_t)Cc * Cc;
  __hip_bfloat16* attb = qkvb + (size_t)M * N3;

  cvt_f32_to_bf16<<<(M * Cc / 8) / 256, 256, 0, stream>>>(x, xb, M * Cc / 8);
  cvt_f32_to_bf16<<<(N3 * Cc / 8) / 256, 256, 0, stream>>>(w_qkv, wqkvb, N3 * Cc / 8);
  cvt_f32_to_bf16<<<(Cc * Cc / 8) / 256, 256, 0, stream>>>(w_fc, wfcb, Cc * Cc / 8);

  // QKV: 128 x 6 = 768 blocks; FC: 128 x 2 = 256 blocks (both %8==0 for XCD swizzle)
  gemm8<true><<<(M / 256) * (N3 / 256), 512, 0, stream>>>(xb, wqkvb, b_qkv, qkvb, M, N3, Cc,
                                                          N3 / 256);
  attn_tok<<<M / 4, 256, 0, stream>>>(qkvb, attb, M, 8192);
  gemm8<false><<<(M / 256) * (Cc / 256), 512, 0, stream>>>(attb, wfcb, b_fc, out, M, Cc, Cc,
                                                           Cc / 256);
}

// Round 4
// 156.592 us; speedup vs baseline: 1.1614x; 1.0730x over previous
//
#include <hip/hip_runtime.h>
#include <hip/hip_bf16.h>
#include <stdint.h>

// MHSA: B=4, N=8192, C=512, HEADS=8, d=64.
// qkv = x @ w_qkv.T + b_qkv ; per-token 8x8 head-mix softmax ; scramble ; @ w_fc.T + b_fc
//
// GEMMs: 256x256 8-phase template (T1..T5) + LDS-shuffled coalesced epilogue.
// R4: fix R3 epilogue OOB (64 -> 16 iters), __syncthreads() for ds_write
// visibility, XOR-swizzled epilogue tile to kill ds bank conflicts.

typedef __bf16 bf16x8 __attribute__((ext_vector_type(8)));
typedef float f32x4 __attribute__((ext_vector_type(4)));

__device__ __forceinline__ unsigned short f2bf(float f) {
  unsigned u = __float_as_uint(f);
  u += 0x7fffu + ((u >> 16) & 1u);  // RNE
  return (unsigned short)(u >> 16);
}
__device__ __forceinline__ unsigned pk2(float a, float b) {
  return (unsigned)f2bf(a) | ((unsigned)f2bf(b) << 16);
}
__device__ __forceinline__ void unpk2(unsigned u, float& a, float& b) {
  a = __uint_as_float(u << 16);
  b = __uint_as_float(u & 0xffff0000u);
}
__device__ __forceinline__ void gload_lds16(const void* g, void* l) {
  __builtin_amdgcn_global_load_lds((const __attribute__((address_space(1))) void*)g,
                                   (__attribute__((address_space(3))) void*)l,
                                   16, 0, 0);
}

// ---------------- f32 -> bf16 convert ----------------
__global__ __launch_bounds__(256) void cvt_f32_to_bf16(const float* __restrict__ in,
                                                       __hip_bfloat16* __restrict__ out,
                                                       int n8) {
  int i = blockIdx.x * 256 + threadIdx.x;
  if (i >= n8) return;
  const float4* p = (const float4*)in;
  float4 a = p[i * 2];
  float4 b = p[i * 2 + 1];
  uint4 o;
  o.x = pk2(a.x, a.y);
  o.y = pk2(a.z, a.w);
  o.z = pk2(b.x, b.y);
  o.w = pk2(b.z, b.w);
  ((uint4*)out)[i] = o;
}

// ---------------- 256x256 8-phase bf16 GEMM, C = A @ B^T + bias ----------------

#define STAGEH(SBUF, ISA, SKH, KT)                                                        \
  do {                                                                                    \
    const __hip_bfloat16* _sp = (ISA) ? Ag : Bg;                                          \
    int _r0 = (ISA) ? bm0 : bn0;                                                          \
    _Pragma("unroll") for (int _j = 0; _j < 2; ++_j) {                                    \
      gload_lds16(_sp + (size_t)(_r0 + srow[_j]) * K + (KT) * 64 + (SKH) * 32 + skoff[_j],\
                  lds + (SBUF) * 65536 + ((ISA) ? 0 : 32768) + (SKH) * 16384 +            \
                      destoff[_j]);                                                       \
    }                                                                                     \
  } while (0)

#define PHASE(BUF, KS, FH, SBUF, SISA, SKH, KT, DOW)                                      \
  do {                                                                                    \
    const char* _ab = lds + (BUF) * 65536 + (KS) * 16384 + wm * 8192 + (FH) * 4096 + pbase;\
    bf16x8 _af0 = *(const bf16x8*)(_ab);                                                  \
    bf16x8 _af1 = *(const bf16x8*)(_ab + 1024);                                           \
    bf16x8 _af2 = *(const bf16x8*)(_ab + 2048);                                           \
    bf16x8 _af3 = *(const bf16x8*)(_ab + 3072);                                           \
    if (FH == 0) {                                                                        \
      const char* _bb = lds + (BUF) * 65536 + 32768 + (KS) * 16384 + wn * 4096 + pbase;   \
      bfr[0] = *(const bf16x8*)(_bb);                                                     \
      bfr[1] = *(const bf16x8*)(_bb + 1024);                                              \
      bfr[2] = *(const bf16x8*)(_bb + 2048);                                              \
      bfr[3] = *(const bf16x8*)(_bb + 3072);                                              \
    }                                                                                     \
    STAGEH(SBUF, SISA, SKH, KT);                                                          \
    __builtin_amdgcn_s_barrier();                                                         \
    asm volatile("s_waitcnt lgkmcnt(0)" ::: "memory");                                    \
    __builtin_amdgcn_sched_barrier(0);                                                    \
    __builtin_amdgcn_s_setprio(1);                                                        \
    _Pragma("unroll") for (int _c = 0; _c < 4; ++_c) {                                    \
      acc[(FH) * 4 + 0][_c] =                                                             \
          __builtin_amdgcn_mfma_f32_16x16x32_bf16(_af0, bfr[_c], acc[(FH) * 4 + 0][_c], 0, 0, 0); \
      acc[(FH) * 4 + 1][_c] =                                                             \
          __builtin_amdgcn_mfma_f32_16x16x32_bf16(_af1, bfr[_c], acc[(FH) * 4 + 1][_c], 0, 0, 0); \
      acc[(FH) * 4 + 2][_c] =                                                             \
          __builtin_amdgcn_mfma_f32_16x16x32_bf16(_af2, bfr[_c], acc[(FH) * 4 + 2][_c], 0, 0, 0); \
      acc[(FH) * 4 + 3][_c] =                                                             \
          __builtin_amdgcn_mfma_f32_16x16x32_bf16(_af3, bfr[_c], acc[(FH) * 4 + 3][_c], 0, 0, 0); \
    }                                                                                     \
    __builtin_amdgcn_s_setprio(0);                                                        \
    if (DOW) {                                                                            \
      asm volatile("s_waitcnt vmcnt(4)" ::: "memory");                                    \
    }                                                                                     \
    __builtin_amdgcn_s_barrier();                                                         \
    __builtin_amdgcn_sched_barrier(0);                                                    \
  } while (0)

template <bool OUT_BF16>
__global__ __launch_bounds__(512, 2) void gemm8(const __hip_bfloat16* __restrict__ Ag,
                                                const __hip_bfloat16* __restrict__ Bg,
                                                const float* __restrict__ bias,
                                                void* __restrict__ C,
                                                int M, int N, int K, int NT) {
  __shared__ __align__(16) char lds[131072];  // [buf:2][A/B][khalf:2][16KiB]

  const int tid = threadIdx.x;
  const int wv = tid >> 6;
  const int ln = tid & 63;
  const int lrow = ln & 15;
  const int kg = ln >> 4;
  const int wm = wv >> 2;   // 0..1 -> 128-row panel
  const int wn = wv & 3;    // 0..3 -> 64-col panel

  // XCD-aware bijective swizzle (gridDim.x % 8 == 0 guaranteed by launch)
  int nwg = gridDim.x;
  int cpx = nwg >> 3;
  int bs = (blockIdx.x & 7) * cpx + (blockIdx.x >> 3);
  const int bm0 = (bs / NT) * 256;
  const int bn0 = (bs % NT) * 256;

  // fragment-read swizzled per-lane base (within a 16KiB K-half region)
  const int pbase = (lrow >> 1) * 128 + ((((lrow & 1) << 2) | kg) ^ ((lrow >> 1) & 7)) * 16;

  // staging geometry: issue j covers linear LDS bytes [j*8192 + wv*1024 + ln*16)
  int srow[2], skoff[2], destoff[2];
#pragma unroll
  for (int j = 0; j < 2; ++j) {
    int L = j * 8192 + wv * 1024 + ln * 16;
    int rp = L >> 7;
    int T = ((L >> 4) & 7) ^ (rp & 7);
    srow[j] = rp * 2 + (T >> 2);
    skoff[j] = (T & 3) * 8;
    destoff[j] = j * 8192 + wv * 1024;  // wave-uniform; HW adds ln*16
  }

  f32x4 acc[8][4] = {};
  bf16x8 bfr[4];

  const int NKT = K >> 6;   // 8 for K=512
  const int NI = NKT >> 1;

  // prologue: tile0 (buf0) fully + tile1 (buf1) K-half0
  STAGEH(0, 1, 0, 0);
  STAGEH(0, 0, 0, 0);
  STAGEH(0, 1, 1, 0);
  STAGEH(0, 0, 1, 0);
  STAGEH(1, 1, 0, 1);
  STAGEH(1, 0, 0, 1);
  asm volatile("s_waitcnt vmcnt(4)" ::: "memory");
  __builtin_amdgcn_s_barrier();
  __builtin_amdgcn_sched_barrier(0);

  for (int i = 0; i < NI; ++i) {
    int kt1 = 2 * i + 1;
    int kt2 = 2 * i + 2 < NKT ? 2 * i + 2 : NKT - 1;
    int kt3 = 2 * i + 3 < NKT ? 2 * i + 3 : NKT - 1;
    PHASE(0, 0, 0, /*stage*/ 1, 1, 1, kt1, 0);
    PHASE(0, 0, 1, /*stage*/ 1, 0, 1, kt1, 0);
    PHASE(0, 1, 0, /*stage*/ 0, 1, 0, kt2, 0);
    PHASE(0, 1, 1, /*stage*/ 0, 0, 0, kt2, 1);
    PHASE(1, 0, 0, /*stage*/ 0, 1, 1, kt2, 0);
    PHASE(1, 0, 1, /*stage*/ 0, 0, 1, kt2, 0);
    PHASE(1, 1, 0, /*stage*/ 1, 1, 0, kt3, 0);
    PHASE(1, 1, 1, /*stage*/ 1, 0, 0, kt3, 1);
  }
  asm volatile("s_waitcnt vmcnt(0)" ::: "memory");
  __syncthreads();  // all DMAs drained + all waves past K-loop; LDS reusable

  if (OUT_BF16) {
    // stage full 256x256 bf16 tile in LDS (exactly 128 KiB), 16B-slot XOR swizzle
    unsigned short* tile = (unsigned short*)lds;
#pragma unroll
    for (int fi = 0; fi < 8; ++fi) {
#pragma unroll
      for (int cj = 0; cj < 4; ++cj) {
        int col = wn * 64 + cj * 16 + lrow;
        float bv = bias[bn0 + col];
#pragma unroll
        for (int r = 0; r < 4; ++r) {
          int row = wm * 128 + fi * 16 + kg * 4 + r;
          int sc = (((col >> 3) ^ (row & 7)) << 3) | (col & 7);
          tile[row * 256 + sc] = f2bf(acc[fi][cj][r] + bv);
        }
      }
    }
    __syncthreads();
#pragma unroll
    for (int it = 0; it < 16; ++it) {
      int id = it * 512 + tid;
      int row = id >> 5;  // 0..255 ; 32 x 16B chunks per row
      int c = id & 31;
      uint4 v = *(const uint4*)(lds + row * 512 + ((c ^ (row & 7)) << 4));
      *(uint4*)((unsigned short*)C + (size_t)(bm0 + row) * N + bn0 + c * 8) = v;
    }
  } else {
    // f32 output: two passes of 128 rows (128 KiB each), 16B-slot XOR swizzle
    float* tilef = (float*)lds;
#pragma unroll
    for (int pass = 0; pass < 2; ++pass) {
      if (wm == pass) {
#pragma unroll
        for (int fi = 0; fi < 8; ++fi) {
#pragma unroll
          for (int cj = 0; cj < 4; ++cj) {
            int col = wn * 64 + cj * 16 + lrow;
            float bv = bias[bn0 + col];
#pragma unroll
            for (int r = 0; r < 4; ++r) {
              int row = fi * 16 + kg * 4 + r;  // 0..127
              int sc = (((col >> 2) ^ (row & 7)) << 2) | (col & 3);
              tilef[row * 256 + sc] = acc[fi][cj][r] + bv;
            }
          }
        }
      }
      __syncthreads();
#pragma unroll
      for (int it = 0; it < 16; ++it) {
        int id = it * 512 + tid;
        int row = id >> 6;  // 0..127 ; 64 x 16B chunks per row
        int c = id & 63;
        uint4 v = *(const uint4*)(lds + row * 1024 + ((c ^ (row & 7)) << 4));
        *(uint4*)((float*)C + (size_t)(bm0 + pass * 128 + row) * N + bn0 + c * 4) = v;
      }
      __syncthreads();
    }
  }
}

// ---------------- per-token attention, 1 token per wave ----------------
__global__ __launch_bounds__(256) void attn_tok(const __hip_bfloat16* __restrict__ qkv,
                                                __hip_bfloat16* __restrict__ outp,
                                                int ntok, int npb) {
  const int wv = threadIdx.x >> 6;
  const int ln = threadIdx.x & 63;
  const int t = blockIdx.x * 4 + wv;
  if (t >= ntok) return;
  const int m = ln & 7;

  const __hip_bfloat16* row = qkv + (size_t)t * 1536;
  uint4 qr = *(const uint4*)(row + ln * 8);
  uint4 kr = *(const uint4*)(row + 512 + ln * 8);
  uint4 vr = *(const uint4*)(row + 1024 + ln * 8);

  float qf[8];
  unpk2(qr.x, qf[0], qf[1]);
  unpk2(qr.y, qf[2], qf[3]);
  unpk2(qr.z, qf[4], qf[5]);
  unpk2(qr.w, qf[6], qf[7]);
  unsigned kw[4] = {kr.x, kr.y, kr.z, kr.w};
  unsigned vw[4] = {vr.x, vr.y, vr.z, vr.w};

  float dt[8];
#pragma unroll
  for (int g = 0; g < 8; ++g) {
    int src = g * 8 + m;
    float s = 0.f;
#pragma unroll
    for (int j4 = 0; j4 < 4; ++j4) {
      unsigned kk = __shfl(kw[j4], src, 64);
      float a, b;
      unpk2(kk, a, b);
      s += qf[j4 * 2] * a + qf[j4 * 2 + 1] * b;
    }
    s += __shfl_xor(s, 1, 64);
    s += __shfl_xor(s, 2, 64);
    s += __shfl_xor(s, 4, 64);
    dt[g] = s;
  }

  float mx = -1e30f;
#pragma unroll
  for (int g = 0; g < 8; ++g) {
    dt[g] = fminf(fmaxf(dt[g] * 0.125f, -50.f), 50.f);
    mx = fmaxf(mx, dt[g]);
  }
  float p[8], ssum = 0.f;
#pragma unroll
  for (int g = 0; g < 8; ++g) {
    p[g] = __expf(dt[g] - mx);
    ssum += p[g];
  }
  float inv = 1.f / ssum;

  float o[8] = {0, 0, 0, 0, 0, 0, 0, 0};
#pragma unroll
  for (int g = 0; g < 8; ++g) {
    int src = g * 8 + m;
    float ag = p[g] * inv;
#pragma unroll
    for (int j4 = 0; j4 < 4; ++j4) {
      unsigned vv = __shfl(vw[j4], src, 64);
      float a, b;
      unpk2(vv, a, b);
      o[j4 * 2] += ag * a;
      o[j4 * 2 + 1] += ag * b;
    }
  }

  const int h = ln >> 3;
  const int b = t / npb, n = t % npb;
  size_t dst = (size_t)b * npb * 512 + (size_t)(h * (npb >> 3) + (n >> 3)) * 512 +
               (size_t)((n & 7) * 64 + m * 8);
  uint4 ov;
  ov.x = pk2(o[0], o[1]);
  ov.y = pk2(o[2], o[3]);
  ov.z = pk2(o[4], o[5]);
  ov.w = pk2(o[6], o[7]);
  *(uint4*)(outp + dst) = ov;
}

// ---------------- launch ----------------
extern "C" void kernel_launch(void* const* d_in, const int* in_sizes, int n_in,
                              void* d_out, int out_size, void* d_ws, size_t ws_size,
                              hipStream_t stream) {
  const float* x = (const float*)d_in[0];
  const float* w_qkv = (const float*)d_in[1];
  const float* b_qkv = (const float*)d_in[2];
  const float* w_fc = (const float*)d_in[3];
  const float* b_fc = (const float*)d_in[4];
  float* out = (float*)d_out;

  const int M = 32768;
  const int Cc = 512, N3 = 1536;

  __hip_bfloat16* xb = (__hip_bfloat16*)d_ws;
  __hip_bfloat16* wqkvb = xb + (size_t)M * Cc;
  __hip_bfloat16* wfcb = wqkvb + (size_t)N3 * Cc;
  __hip_bfloat16* qkvb = wfcb + (size_t)Cc * Cc;
  __hip_bfloat16* attb = qkvb + (size_t)M * N3;

  cvt_f32_to_bf16<<<(M * Cc / 8) / 256, 256, 0, stream>>>(x, xb, M * Cc / 8);
  cvt_f32_to_bf16<<<(N3 * Cc / 8) / 256, 256, 0, stream>>>(w_qkv, wqkvb, N3 * Cc / 8);
  cvt_f32_to_bf16<<<(Cc * Cc / 8) / 256, 256, 0, stream>>>(w_fc, wfcb, Cc * Cc / 8);

  gemm8<true><<<(M / 256) * (N3 / 256), 512, 0, stream>>>(xb, wqkvb, b_qkv, qkvb, M, N3, Cc,
                                                          N3 / 256);
  attn_tok<<<M / 4, 256, 0, stream>>>(qkvb, attb, M, 8192);
  gemm8<false><<<(M / 256) * (Cc / 256), 512, 0, stream>>>(attb, wfcb, b_fc, out, M, Cc, Cc,
                                                           Cc / 256);
}

// Round 5
// 152.414 us; speedup vs baseline: 1.1932x; 1.0274x over previous
//
#include <hip/hip_runtime.h>
#include <hip/hip_bf16.h>
#include <stdint.h>

// MHSA: B=4, N=8192, C=512, HEADS=8, d=64.
// R5: GEMMs restructured for 2 blocks/CU (16 waves/CU): 256x128 tile, 8 waves
// (4Mx2N, wave-tile 64x64 -> acc 64 VGPR, total <=128 regs), BK=32 double-buffer
// (48 KiB LDS), 2-phase counted loop. Cross-block overlap hides barrier/DMA
// stalls that capped R4 at MfmaUtil 23% (1 block/CU, occupancy 20.8%).

typedef __bf16 bf16x8 __attribute__((ext_vector_type(8)));
typedef float f32x4 __attribute__((ext_vector_type(4)));

__device__ __forceinline__ unsigned short f2bf(float f) {
  unsigned u = __float_as_uint(f);
  u += 0x7fffu + ((u >> 16) & 1u);  // RNE
  return (unsigned short)(u >> 16);
}
__device__ __forceinline__ unsigned pk2(float a, float b) {
  return (unsigned)f2bf(a) | ((unsigned)f2bf(b) << 16);
}
__device__ __forceinline__ void unpk2(unsigned u, float& a, float& b) {
  a = __uint_as_float(u << 16);
  b = __uint_as_float(u & 0xffff0000u);
}
__device__ __forceinline__ void gload_lds16(const void* g, void* l) {
  __builtin_amdgcn_global_load_lds((const __attribute__((address_space(1))) void*)g,
                                   (__attribute__((address_space(3))) void*)l,
                                   16, 0, 0);
}

// ---------------- f32 -> bf16 convert ----------------
__global__ __launch_bounds__(256) void cvt_f32_to_bf16(const float* __restrict__ in,
                                                       __hip_bfloat16* __restrict__ out,
                                                       int n8) {
  int i = blockIdx.x * 256 + threadIdx.x;
  if (i >= n8) return;
  const float4* p = (const float4*)in;
  float4 a = p[i * 2];
  float4 b = p[i * 2 + 1];
  uint4 o;
  o.x = pk2(a.x, a.y);
  o.y = pk2(a.z, a.w);
  o.z = pk2(b.x, b.y);
  o.w = pk2(b.z, b.w);
  ((uint4*)out)[i] = o;
}

// ---------------- 256x128 2-phase bf16 GEMM, C = A @ B^T + bias ----------------
// A: M x K bf16, B: N x K bf16 (row-major), bias: N f32.
// LDS per buffer: A-region 16 KiB (256r x 32k) + B-region 8 KiB (128r x 32k).
// Swizzle within region: phys(row,kg) = (row>>1)*128 + ((((row&1)<<2)|kg)^((row>>1)&7))*16.

#define STG(S, BUF)                                                                       \
  do {                                                                                    \
    int _k0 = (S) * 32;                                                                   \
    gload_lds16(Ag + (size_t)(bm0 + srowA0) * K + _k0 + skofA0,                           \
                lds + (BUF) * 24576 + dstA0);                                             \
    gload_lds16(Ag + (size_t)(bm0 + srowA1) * K + _k0 + skofA1,                           \
                lds + (BUF) * 24576 + dstA1);                                             \
    gload_lds16(Bg + (size_t)(bn0 + srowB) * K + _k0 + skofB,                             \
                lds + (BUF) * 24576 + 16384 + dstB);                                      \
  } while (0)

template <bool OUT_BF16>
__global__ __launch_bounds__(512, 4) void gemm2p(const __hip_bfloat16* __restrict__ Ag,
                                                 const __hip_bfloat16* __restrict__ Bg,
                                                 const float* __restrict__ bias,
                                                 void* __restrict__ C,
                                                 int M, int N, int K, int NT) {
  __shared__ __align__(16) char lds[65536];  // 48 KiB pipeline, 64 KiB epilogue

  const int tid = threadIdx.x;
  const int wv = tid >> 6;
  const int ln = tid & 63;
  const int lrow = ln & 15;
  const int kg = ln >> 4;
  const int wm = wv >> 1;  // 0..3 -> 64-row panel
  const int wn = wv & 1;   // 0..1 -> 64-col panel

  // XCD-aware bijective swizzle (gridDim.x % 8 == 0)
  int nwg = gridDim.x;
  int cpx = nwg >> 3;
  int bs = (blockIdx.x & 7) * cpx + (blockIdx.x >> 3);
  const int bm0 = (bs / NT) * 256;
  const int bn0 = (bs % NT) * 128;

  const int pbase = (lrow >> 1) * 128 + ((((lrow & 1) << 2) | kg) ^ ((lrow >> 1) & 7)) * 16;

  // staging maps (pre-swizzled global source, linear LDS dest)
  int srowA0, skofA0, dstA0, srowA1, skofA1, dstA1, srowB, skofB, dstB;
  {
    int L0 = wv * 1024 + ln * 16;
    int rp0 = L0 >> 7, T0 = ((L0 >> 4) & 7) ^ (rp0 & 7);
    srowA0 = rp0 * 2 + (T0 >> 2);
    skofA0 = (T0 & 3) * 8;
    dstA0 = wv * 1024;
    int L1 = 8192 + L0;
    int rp1 = L1 >> 7, T1 = ((L1 >> 4) & 7) ^ (rp1 & 7);
    srowA1 = rp1 * 2 + (T1 >> 2);
    skofA1 = (T1 & 3) * 8;
    dstA1 = 8192 + wv * 1024;
    srowB = srowA0;
    skofB = skofA0;
    dstB = wv * 1024;
  }

  f32x4 acc[4][4] = {};

  const int NKT = K >> 5;  // 16 for K=512

  STG(0, 0);
  asm volatile("s_waitcnt vmcnt(0)" ::: "memory");
  __builtin_amdgcn_s_barrier();
  __builtin_amdgcn_sched_barrier(0);

  for (int s = 0; s < NKT; ++s) {
    int b = s & 1;
    if (s + 1 < NKT) STG(s + 1, b ^ 1);
    {
      const char* _ab = lds + b * 24576 + wm * 4096 + pbase;
      const char* _bb = lds + b * 24576 + 16384 + wn * 4096 + pbase;
      bf16x8 a0 = *(const bf16x8*)(_ab);
      bf16x8 a1 = *(const bf16x8*)(_ab + 1024);
      bf16x8 a2 = *(const bf16x8*)(_ab + 2048);
      bf16x8 a3 = *(const bf16x8*)(_ab + 3072);
      bf16x8 b0 = *(const bf16x8*)(_bb);
      bf16x8 b1 = *(const bf16x8*)(_bb + 1024);
      bf16x8 b2 = *(const bf16x8*)(_bb + 2048);
      bf16x8 b3 = *(const bf16x8*)(_bb + 3072);
      asm volatile("s_waitcnt lgkmcnt(0)" ::: "memory");
      __builtin_amdgcn_sched_barrier(0);
      __builtin_amdgcn_s_setprio(1);
      acc[0][0] = __builtin_amdgcn_mfma_f32_16x16x32_bf16(a0, b0, acc[0][0], 0, 0, 0);
      acc[0][1] = __builtin_amdgcn_mfma_f32_16x16x32_bf16(a0, b1, acc[0][1], 0, 0, 0);
      acc[0][2] = __builtin_amdgcn_mfma_f32_16x16x32_bf16(a0, b2, acc[0][2], 0, 0, 0);
      acc[0][3] = __builtin_amdgcn_mfma_f32_16x16x32_bf16(a0, b3, acc[0][3], 0, 0, 0);
      acc[1][0] = __builtin_amdgcn_mfma_f32_16x16x32_bf16(a1, b0, acc[1][0], 0, 0, 0);
      acc[1][1] = __builtin_amdgcn_mfma_f32_16x16x32_bf16(a1, b1, acc[1][1], 0, 0, 0);
      acc[1][2] = __builtin_amdgcn_mfma_f32_16x16x32_bf16(a1, b2, acc[1][2], 0, 0, 0);
      acc[1][3] = __builtin_amdgcn_mfma_f32_16x16x32_bf16(a1, b3, acc[1][3], 0, 0, 0);
      acc[2][0] = __builtin_amdgcn_mfma_f32_16x16x32_bf16(a2, b0, acc[2][0], 0, 0, 0);
      acc[2][1] = __builtin_amdgcn_mfma_f32_16x16x32_bf16(a2, b1, acc[2][1], 0, 0, 0);
      acc[2][2] = __builtin_amdgcn_mfma_f32_16x16x32_bf16(a2, b2, acc[2][2], 0, 0, 0);
      acc[2][3] = __builtin_amdgcn_mfma_f32_16x16x32_bf16(a2, b3, acc[2][3], 0, 0, 0);
      acc[3][0] = __builtin_amdgcn_mfma_f32_16x16x32_bf16(a3, b0, acc[3][0], 0, 0, 0);
      acc[3][1] = __builtin_amdgcn_mfma_f32_16x16x32_bf16(a3, b1, acc[3][1], 0, 0, 0);
      acc[3][2] = __builtin_amdgcn_mfma_f32_16x16x32_bf16(a3, b2, acc[3][2], 0, 0, 0);
      acc[3][3] = __builtin_amdgcn_mfma_f32_16x16x32_bf16(a3, b3, acc[3][3], 0, 0, 0);
      __builtin_amdgcn_s_setprio(0);
    }
    asm volatile("s_waitcnt vmcnt(0)" ::: "memory");
    __builtin_amdgcn_s_barrier();
    __builtin_amdgcn_sched_barrier(0);
  }

  // ---- epilogue: LDS-shuffled coalesced writeout ----
  if (OUT_BF16) {
    unsigned short* tile = (unsigned short*)lds;  // 256 x 128 bf16 = 64 KiB
#pragma unroll
    for (int fi = 0; fi < 4; ++fi) {
#pragma unroll
      for (int cj = 0; cj < 4; ++cj) {
        int col = wn * 64 + cj * 16 + lrow;
        float bv = bias[bn0 + col];
#pragma unroll
        for (int r = 0; r < 4; ++r) {
          int row = wm * 64 + fi * 16 + kg * 4 + r;
          int sc = (((col >> 3) ^ (row & 7)) << 3) | (col & 7);
          tile[row * 128 + sc] = f2bf(acc[fi][cj][r] + bv);
        }
      }
    }
    __syncthreads();
#pragma unroll
    for (int it = 0; it < 8; ++it) {
      int id = it * 512 + tid;
      int row = id >> 4;  // 0..255 ; 16 x 16B chunks/row
      int c = id & 15;
      uint4 v = *(const uint4*)(lds + row * 256 + ((c ^ (row & 7)) << 4));
      *(uint4*)((unsigned short*)C + (size_t)(bm0 + row) * N + bn0 + c * 8) = v;
    }
  } else {
    float* tilef = (float*)lds;  // 128 x 128 f32 = 64 KiB per pass
#pragma unroll
    for (int pass = 0; pass < 2; ++pass) {
      if ((wm >> 1) == pass) {
#pragma unroll
        for (int fi = 0; fi < 4; ++fi) {
#pragma unroll
          for (int cj = 0; cj < 4; ++cj) {
            int col = wn * 64 + cj * 16 + lrow;
            float bv = bias[bn0 + col];
#pragma unroll
            for (int r = 0; r < 4; ++r) {
              int row = (wm & 1) * 64 + fi * 16 + kg * 4 + r;  // 0..127
              int sc = (((col >> 2) ^ (row & 7)) << 2) | (col & 3);
              tilef[row * 128 + sc] = acc[fi][cj][r] + bv;
            }
          }
        }
      }
      __syncthreads();
#pragma unroll
      for (int it = 0; it < 8; ++it) {
        int id = it * 512 + tid;
        int row = id >> 5;  // 0..127 ; 32 x 16B chunks/row
        int c = id & 31;
        uint4 v = *(const uint4*)(lds + row * 512 + ((c ^ (row & 7)) << 4));
        *(uint4*)((float*)C + (size_t)(bm0 + pass * 128 + row) * N + bn0 + c * 4) = v;
      }
      __syncthreads();
    }
  }
}

// ---------------- per-token attention, 1 token per wave ----------------
__global__ __launch_bounds__(256) void attn_tok(const __hip_bfloat16* __restrict__ qkv,
                                                __hip_bfloat16* __restrict__ outp,
                                                int ntok, int npb) {
  const int wv = threadIdx.x >> 6;
  const int ln = threadIdx.x & 63;
  const int t = blockIdx.x * 4 + wv;
  if (t >= ntok) return;
  const int m = ln & 7;

  const __hip_bfloat16* row = qkv + (size_t)t * 1536;
  uint4 qr = *(const uint4*)(row + ln * 8);
  uint4 kr = *(const uint4*)(row + 512 + ln * 8);
  uint4 vr = *(const uint4*)(row + 1024 + ln * 8);

  float qf[8];
  unpk2(qr.x, qf[0], qf[1]);
  unpk2(qr.y, qf[2], qf[3]);
  unpk2(qr.z, qf[4], qf[5]);
  unpk2(qr.w, qf[6], qf[7]);
  unsigned kw[4] = {kr.x, kr.y, kr.z, kr.w};
  unsigned vw[4] = {vr.x, vr.y, vr.z, vr.w};

  float dt[8];
#pragma unroll
  for (int g = 0; g < 8; ++g) {
    int src = g * 8 + m;
    float s = 0.f;
#pragma unroll
    for (int j4 = 0; j4 < 4; ++j4) {
      unsigned kk = __shfl(kw[j4], src, 64);
      float a, b;
      unpk2(kk, a, b);
      s += qf[j4 * 2] * a + qf[j4 * 2 + 1] * b;
    }
    s += __shfl_xor(s, 1, 64);
    s += __shfl_xor(s, 2, 64);
    s += __shfl_xor(s, 4, 64);
    dt[g] = s;
  }

  float mx = -1e30f;
#pragma unroll
  for (int g = 0; g < 8; ++g) {
    dt[g] = fminf(fmaxf(dt[g] * 0.125f, -50.f), 50.f);
    mx = fmaxf(mx, dt[g]);
  }
  float p[8], ssum = 0.f;
#pragma unroll
  for (int g = 0; g < 8; ++g) {
    p[g] = __expf(dt[g] - mx);
    ssum += p[g];
  }
  float inv = 1.f / ssum;

  float o[8] = {0, 0, 0, 0, 0, 0, 0, 0};
#pragma unroll
  for (int g = 0; g < 8; ++g) {
    int src = g * 8 + m;
    float ag = p[g] * inv;
#pragma unroll
    for (int j4 = 0; j4 < 4; ++j4) {
      unsigned vv = __shfl(vw[j4], src, 64);
      float a, b;
      unpk2(vv, a, b);
      o[j4 * 2] += ag * a;
      o[j4 * 2 + 1] += ag * b;
    }
  }

  const int h = ln >> 3;
  const int b = t / npb, n = t % npb;
  size_t dst = (size_t)b * npb * 512 + (size_t)(h * (npb >> 3) + (n >> 3)) * 512 +
               (size_t)((n & 7) * 64 + m * 8);
  uint4 ov;
  ov.x = pk2(o[0], o[1]);
  ov.y = pk2(o[2], o[3]);
  ov.z = pk2(o[4], o[5]);
  ov.w = pk2(o[6], o[7]);
  *(uint4*)(outp + dst) = ov;
}

// ---------------- launch ----------------
extern "C" void kernel_launch(void* const* d_in, const int* in_sizes, int n_in,
                              void* d_out, int out_size, void* d_ws, size_t ws_size,
                              hipStream_t stream) {
  const float* x = (const float*)d_in[0];
  const float* w_qkv = (const float*)d_in[1];
  const float* b_qkv = (const float*)d_in[2];
  const float* w_fc = (const float*)d_in[3];
  const float* b_fc = (const float*)d_in[4];
  float* out = (float*)d_out;

  const int M = 32768;
  const int Cc = 512, N3 = 1536;

  __hip_bfloat16* xb = (__hip_bfloat16*)d_ws;
  __hip_bfloat16* wqkvb = xb + (size_t)M * Cc;
  __hip_bfloat16* wfcb = wqkvb + (size_t)N3 * Cc;
  __hip_bfloat16* qkvb = wfcb + (size_t)Cc * Cc;
  __hip_bfloat16* attb = qkvb + (size_t)M * N3;

  cvt_f32_to_bf16<<<(M * Cc / 8) / 256, 256, 0, stream>>>(x, xb, M * Cc / 8);
  cvt_f32_to_bf16<<<(N3 * Cc / 8) / 256, 256, 0, stream>>>(w_qkv, wqkvb, N3 * Cc / 8);
  cvt_f32_to_bf16<<<(Cc * Cc / 8) / 256, 256, 0, stream>>>(w_fc, wfcb, Cc * Cc / 8);

  // QKV: (32768/256)x(1536/128) = 1536 blocks ; FC: 128x4 = 512 blocks
  gemm2p<true><<<(M / 256) * (N3 / 128), 512, 0, stream>>>(xb, wqkvb, b_qkv, qkvb, M, N3, Cc,
                                                           N3 / 128);
  attn_tok<<<M / 4, 256, 0, stream>>>(qkvb, attb, M, 8192);
  gemm2p<false><<<(M / 256) * (Cc / 128), 512, 0, stream>>>(attb, wfcb, b_fc, out, M, Cc, Cc,
                                                            Cc / 128);
}

// Round 6
// 147.362 us; speedup vs baseline: 1.2341x; 1.0343x over previous
//
#include <hip/hip_runtime.h>
#include <hip/hip_bf16.h>
#include <stdint.h>

// MHSA: B=4, N=8192, C=512, HEADS=8, d=64.
// R6: GEMM K-loop -> 3-buffer depth-2 counted-vmcnt pipeline (T3/T4):
// one barrier per K-step, vmcnt(3) instead of vmcnt(0) drain, STG(s+2)
// issued right after the barrier. 256x128 tile, 8 waves (4Mx2N), BK=32,
// LDS 72 KiB -> 2 blocks/CU. R5 measured MfmaUtil 29% @ 0.5 TB/s replay BW
// = pure exposed-latency stall; this hides it under ~2 steps of MFMA.

typedef __bf16 bf16x8 __attribute__((ext_vector_type(8)));
typedef float f32x4 __attribute__((ext_vector_type(4)));

__device__ __forceinline__ unsigned short f2bf(float f) {
  unsigned u = __float_as_uint(f);
  u += 0x7fffu + ((u >> 16) & 1u);  // RNE
  return (unsigned short)(u >> 16);
}
__device__ __forceinline__ unsigned pk2(float a, float b) {
  return (unsigned)f2bf(a) | ((unsigned)f2bf(b) << 16);
}
__device__ __forceinline__ void unpk2(unsigned u, float& a, float& b) {
  a = __uint_as_float(u << 16);
  b = __uint_as_float(u & 0xffff0000u);
}
__device__ __forceinline__ void gload_lds16(const void* g, void* l) {
  __builtin_amdgcn_global_load_lds((const __attribute__((address_space(1))) void*)g,
                                   (__attribute__((address_space(3))) void*)l,
                                   16, 0, 0);
}

// ---------------- f32 -> bf16 convert ----------------
__global__ __launch_bounds__(256) void cvt_f32_to_bf16(const float* __restrict__ in,
                                                       __hip_bfloat16* __restrict__ out,
                                                       int n8) {
  int i = blockIdx.x * 256 + threadIdx.x;
  if (i >= n8) return;
  const float4* p = (const float4*)in;
  float4 a = p[i * 2];
  float4 b = p[i * 2 + 1];
  uint4 o;
  o.x = pk2(a.x, a.y);
  o.y = pk2(a.z, a.w);
  o.z = pk2(b.x, b.y);
  o.w = pk2(b.z, b.w);
  ((uint4*)out)[i] = o;
}

// ---------------- 256x128 pipelined bf16 GEMM, C = A @ B^T + bias ----------------
// LDS per buffer: A 16 KiB (256r x 32k) + B 8 KiB (128r x 32k); 3 buffers.
// Region swizzle: phys(row,kg) = (row>>1)*128 + ((((row&1)<<2)|kg)^((row>>1)&7))*16.

#define STG(S, BUF)                                                                       \
  do {                                                                                    \
    int _k0 = (S) * 32;                                                                   \
    gload_lds16(Ag + (size_t)(bm0 + srowA0) * KDIM + _k0 + skofA0,                        \
                lds + (BUF) * 24576 + dstA0);                                             \
    gload_lds16(Ag + (size_t)(bm0 + srowA1) * KDIM + _k0 + skofA1,                        \
                lds + (BUF) * 24576 + dstA1);                                             \
    gload_lds16(Bg + (size_t)(bn0 + srowB) * KDIM + _k0 + skofB,                          \
                lds + (BUF) * 24576 + 16384 + dstB);                                      \
  } while (0)

template <bool OUT_BF16, int KDIM>
__global__ __launch_bounds__(512, 4) void gemm3b(const __hip_bfloat16* __restrict__ Ag,
                                                 const __hip_bfloat16* __restrict__ Bg,
                                                 const float* __restrict__ bias,
                                                 void* __restrict__ C,
                                                 int M, int N, int NT) {
  __shared__ __align__(16) char lds[73728];  // 3 x 24 KiB pipeline; 64 KiB epilogue

  const int tid = threadIdx.x;
  const int wv = tid >> 6;
  const int ln = tid & 63;
  const int lrow = ln & 15;
  const int kg = ln >> 4;
  const int wm = wv >> 1;  // 0..3 -> 64-row panel
  const int wn = wv & 1;   // 0..1 -> 64-col panel

  // XCD-aware bijective swizzle (gridDim.x % 8 == 0)
  int nwg = gridDim.x;
  int cpx = nwg >> 3;
  int bs = (blockIdx.x & 7) * cpx + (blockIdx.x >> 3);
  const int bm0 = (bs / NT) * 256;
  const int bn0 = (bs % NT) * 128;

  const int pbase = (lrow >> 1) * 128 + ((((lrow & 1) << 2) | kg) ^ ((lrow >> 1) & 7)) * 16;

  // staging maps (pre-swizzled global source, linear LDS dest)
  int srowA0, skofA0, dstA0, srowA1, skofA1, dstA1, srowB, skofB, dstB;
  {
    int L0 = wv * 1024 + ln * 16;
    int rp0 = L0 >> 7, T0 = ((L0 >> 4) & 7) ^ (rp0 & 7);
    srowA0 = rp0 * 2 + (T0 >> 2);
    skofA0 = (T0 & 3) * 8;
    dstA0 = wv * 1024;
    int L1 = 8192 + L0;
    int rp1 = L1 >> 7, T1 = ((L1 >> 4) & 7) ^ (rp1 & 7);
    srowA1 = rp1 * 2 + (T1 >> 2);
    skofA1 = (T1 & 3) * 8;
    dstA1 = 8192 + wv * 1024;
    srowB = srowA0;
    skofB = skofA0;
    dstB = wv * 1024;
  }

  f32x4 acc[4][4] = {};

  constexpr int NKT = KDIM >> 5;  // 16 for K=512

  STG(0, 0);
  STG(1, 1);

#pragma unroll
  for (int s = 0; s < NKT; ++s) {
    if (s == NKT - 1) {
      asm volatile("s_waitcnt vmcnt(0)" ::: "memory");
    } else {
      asm volatile("s_waitcnt vmcnt(3)" ::: "memory");
    }
    __builtin_amdgcn_s_barrier();
    __builtin_amdgcn_sched_barrier(0);
    if (s + 2 < NKT) STG(s + 2, (s + 2) % 3);
    {
      const char* _ab = lds + (s % 3) * 24576 + wm * 4096 + pbase;
      const char* _bb = lds + (s % 3) * 24576 + 16384 + wn * 4096 + pbase;
      bf16x8 a0 = *(const bf16x8*)(_ab);
      bf16x8 a1 = *(const bf16x8*)(_ab + 1024);
      bf16x8 a2 = *(const bf16x8*)(_ab + 2048);
      bf16x8 a3 = *(const bf16x8*)(_ab + 3072);
      bf16x8 b0 = *(const bf16x8*)(_bb);
      bf16x8 b1 = *(const bf16x8*)(_bb + 1024);
      bf16x8 b2 = *(const bf16x8*)(_bb + 2048);
      bf16x8 b3 = *(const bf16x8*)(_bb + 3072);
      asm volatile("s_waitcnt lgkmcnt(0)" ::: "memory");
      __builtin_amdgcn_sched_barrier(0);
      __builtin_amdgcn_s_setprio(1);
      acc[0][0] = __builtin_amdgcn_mfma_f32_16x16x32_bf16(a0, b0, acc[0][0], 0, 0, 0);
      acc[0][1] = __builtin_amdgcn_mfma_f32_16x16x32_bf16(a0, b1, acc[0][1], 0, 0, 0);
      acc[0][2] = __builtin_amdgcn_mfma_f32_16x16x32_bf16(a0, b2, acc[0][2], 0, 0, 0);
      acc[0][3] = __builtin_amdgcn_mfma_f32_16x16x32_bf16(a0, b3, acc[0][3], 0, 0, 0);
      acc[1][0] = __builtin_amdgcn_mfma_f32_16x16x32_bf16(a1, b0, acc[1][0], 0, 0, 0);
      acc[1][1] = __builtin_amdgcn_mfma_f32_16x16x32_bf16(a1, b1, acc[1][1], 0, 0, 0);
      acc[1][2] = __builtin_amdgcn_mfma_f32_16x16x32_bf16(a1, b2, acc[1][2], 0, 0, 0);
      acc[1][3] = __builtin_amdgcn_mfma_f32_16x16x32_bf16(a1, b3, acc[1][3], 0, 0, 0);
      acc[2][0] = __builtin_amdgcn_mfma_f32_16x16x32_bf16(a2, b0, acc[2][0], 0, 0, 0);
      acc[2][1] = __builtin_amdgcn_mfma_f32_16x16x32_bf16(a2, b1, acc[2][1], 0, 0, 0);
      acc[2][2] = __builtin_amdgcn_mfma_f32_16x16x32_bf16(a2, b2, acc[2][2], 0, 0, 0);
      acc[2][3] = __builtin_amdgcn_mfma_f32_16x16x32_bf16(a2, b3, acc[2][3], 0, 0, 0);
      acc[3][0] = __builtin_amdgcn_mfma_f32_16x16x32_bf16(a3, b0, acc[3][0], 0, 0, 0);
      acc[3][1] = __builtin_amdgcn_mfma_f32_16x16x32_bf16(a3, b1, acc[3][1], 0, 0, 0);
      acc[3][2] = __builtin_amdgcn_mfma_f32_16x16x32_bf16(a3, b2, acc[3][2], 0, 0, 0);
      acc[3][3] = __builtin_amdgcn_mfma_f32_16x16x32_bf16(a3, b3, acc[3][3], 0, 0, 0);
      __builtin_amdgcn_s_setprio(0);
    }
  }
  __syncthreads();  // last-step LDS reads done in all waves; LDS reusable

  // ---- epilogue: LDS-shuffled coalesced writeout ----
  if (OUT_BF16) {
    unsigned short* tile = (unsigned short*)lds;  // 256 x 128 bf16 = 64 KiB
#pragma unroll
    for (int fi = 0; fi < 4; ++fi) {
#pragma unroll
      for (int cj = 0; cj < 4; ++cj) {
        int col = wn * 64 + cj * 16 + lrow;
        float bv = bias[bn0 + col];
#pragma unroll
        for (int r = 0; r < 4; ++r) {
          int row = wm * 64 + fi * 16 + kg * 4 + r;
          int sc = (((col >> 3) ^ (row & 7)) << 3) | (col & 7);
          tile[row * 128 + sc] = f2bf(acc[fi][cj][r] + bv);
        }
      }
    }
    __syncthreads();
#pragma unroll
    for (int it = 0; it < 8; ++it) {
      int id = it * 512 + tid;
      int row = id >> 4;  // 0..255 ; 16 x 16B chunks/row
      int c = id & 15;
      uint4 v = *(const uint4*)(lds + row * 256 + ((c ^ (row & 7)) << 4));
      *(uint4*)((unsigned short*)C + (size_t)(bm0 + row) * N + bn0 + c * 8) = v;
    }
  } else {
    float* tilef = (float*)lds;  // 128 x 128 f32 = 64 KiB per pass
#pragma unroll
    for (int pass = 0; pass < 2; ++pass) {
      if ((wm >> 1) == pass) {
#pragma unroll
        for (int fi = 0; fi < 4; ++fi) {
#pragma unroll
          for (int cj = 0; cj < 4; ++cj) {
            int col = wn * 64 + cj * 16 + lrow;
            float bv = bias[bn0 + col];
#pragma unroll
            for (int r = 0; r < 4; ++r) {
              int row = (wm & 1) * 64 + fi * 16 + kg * 4 + r;  // 0..127
              int sc = (((col >> 2) ^ (row & 7)) << 2) | (col & 3);
              tilef[row * 128 + sc] = acc[fi][cj][r] + bv;
            }
          }
        }
      }
      __syncthreads();
#pragma unroll
      for (int it = 0; it < 8; ++it) {
        int id = it * 512 + tid;
        int row = id >> 5;  // 0..127 ; 32 x 16B chunks/row
        int c = id & 31;
        uint4 v = *(const uint4*)(lds + row * 512 + ((c ^ (row & 7)) << 4));
        *(uint4*)((float*)C + (size_t)(bm0 + pass * 128 + row) * N + bn0 + c * 4) = v;
      }
      __syncthreads();
    }
  }
}

// ---------------- per-token attention, 1 token per wave ----------------
__global__ __launch_bounds__(256) void attn_tok(const __hip_bfloat16* __restrict__ qkv,
                                                __hip_bfloat16* __restrict__ outp,
                                                int ntok, int npb) {
  const int wv = threadIdx.x >> 6;
  const int ln = threadIdx.x & 63;
  const int t = blockIdx.x * 4 + wv;
  if (t >= ntok) return;
  const int m = ln & 7;

  const __hip_bfloat16* row = qkv + (size_t)t * 1536;
  uint4 qr = *(const uint4*)(row + ln * 8);
  uint4 kr = *(const uint4*)(row + 512 + ln * 8);
  uint4 vr = *(const uint4*)(row + 1024 + ln * 8);

  float qf[8];
  unpk2(qr.x, qf[0], qf[1]);
  unpk2(qr.y, qf[2], qf[3]);
  unpk2(qr.z, qf[4], qf[5]);
  unpk2(qr.w, qf[6], qf[7]);
  unsigned kw[4] = {kr.x, kr.y, kr.z, kr.w};
  unsigned vw[4] = {vr.x, vr.y, vr.z, vr.w};

  float dt[8];
#pragma unroll
  for (int g = 0; g < 8; ++g) {
    int src = g * 8 + m;
    float s = 0.f;
#pragma unroll
    for (int j4 = 0; j4 < 4; ++j4) {
      unsigned kk = __shfl(kw[j4], src, 64);
      float a, b;
      unpk2(kk, a, b);
      s += qf[j4 * 2] * a + qf[j4 * 2 + 1] * b;
    }
    s += __shfl_xor(s, 1, 64);
    s += __shfl_xor(s, 2, 64);
    s += __shfl_xor(s, 4, 64);
    dt[g] = s;
  }

  float mx = -1e30f;
#pragma unroll
  for (int g = 0; g < 8; ++g) {
    dt[g] = fminf(fmaxf(dt[g] * 0.125f, -50.f), 50.f);
    mx = fmaxf(mx, dt[g]);
  }
  float p[8], ssum = 0.f;
#pragma unroll
  for (int g = 0; g < 8; ++g) {
    p[g] = __expf(dt[g] - mx);
    ssum += p[g];
  }
  float inv = 1.f / ssum;

  float o[8] = {0, 0, 0, 0, 0, 0, 0, 0};
#pragma unroll
  for (int g = 0; g < 8; ++g) {
    int src = g * 8 + m;
    float ag = p[g] * inv;
#pragma unroll
    for (int j4 = 0; j4 < 4; ++j4) {
      unsigned vv = __shfl(vw[j4], src, 64);
      float a, b;
      unpk2(vv, a, b);
      o[j4 * 2] += ag * a;
      o[j4 * 2 + 1] += ag * b;
    }
  }

  const int h = ln >> 3;
  const int b = t / npb, n = t % npb;
  size_t dst = (size_t)b * npb * 512 + (size_t)(h * (npb >> 3) + (n >> 3)) * 512 +
               (size_t)((n & 7) * 64 + m * 8);
  uint4 ov;
  ov.x = pk2(o[0], o[1]);
  ov.y = pk2(o[2], o[3]);
  ov.z = pk2(o[4], o[5]);
  ov.w = pk2(o[6], o[7]);
  *(uint4*)(outp + dst) = ov;
}

// ---------------- launch ----------------
extern "C" void kernel_launch(void* const* d_in, const int* in_sizes, int n_in,
                              void* d_out, int out_size, void* d_ws, size_t ws_size,
                              hipStream_t stream) {
  const float* x = (const float*)d_in[0];
  const float* w_qkv = (const float*)d_in[1];
  const float* b_qkv = (const float*)d_in[2];
  const float* w_fc = (const float*)d_in[3];
  const float* b_fc = (const float*)d_in[4];
  float* out = (float*)d_out;

  const int M = 32768;
  const int Cc = 512, N3 = 1536;

  __hip_bfloat16* xb = (__hip_bfloat16*)d_ws;
  __hip_bfloat16* wqkvb = xb + (size_t)M * Cc;
  __hip_bfloat16* wfcb = wqkvb + (size_t)N3 * Cc;
  __hip_bfloat16* qkvb = wfcb + (size_t)Cc * Cc;
  __hip_bfloat16* attb = qkvb + (size_t)M * N3;

  cvt_f32_to_bf16<<<(M * Cc / 8) / 256, 256, 0, stream>>>(x, xb, M * Cc / 8);
  cvt_f32_to_bf16<<<(N3 * Cc / 8) / 256, 256, 0, stream>>>(w_qkv, wqkvb, N3 * Cc / 8);
  cvt_f32_to_bf16<<<(Cc * Cc / 8) / 256, 256, 0, stream>>>(w_fc, wfcb, Cc * Cc / 8);

  // QKV: (32768/256)x(1536/128) = 1536 blocks ; FC: 128x4 = 512 blocks
  gemm3b<true, 512><<<(M / 256) * (N3 / 128), 512, 0, stream>>>(xb, wqkvb, b_qkv, qkvb, M, N3,
                                                                N3 / 128);
  attn_tok<<<M / 4, 256, 0, stream>>>(qkvb, attb, M, 8192);
  gemm3b<false, 512><<<(M / 256) * (Cc / 128), 512, 0, stream>>>(attb, wfcb, b_fc, out, M, Cc,
                                                                 Cc / 128);
}